// Round 1
// 178.367 us; speedup vs baseline: 1.0602x; 1.0602x over previous
//
#include <hip/hip_runtime.h>

#define HW_ (512 * 512)

typedef __attribute__((ext_vector_type(8))) _Float16 half8;
typedef __attribute__((ext_vector_type(4))) _Float16 half4;
typedef __attribute__((ext_vector_type(4))) float    f32x4;

// ---------------------------------------------------------------------------
// K0: all launch-constant tables, in MFMA fragment order.
//  bF1[ks16][mt8][lane64][j8]  : w-FFT basis rows 0..63 cos, 64..127 sin
//  bF2[t32][kt4][lane64][j8]   : h-FFT operand A2[kh][kglob] (cos | sin halves)
//  whF[t128][ft16][lane64][j8] : fc_w * 16, f16
// ---------------------------------------------------------------------------
__global__ __launch_bounds__(256) void k_prep(const float* __restrict__ fc_w,
                                              _Float16* __restrict__ bF1,
                                              _Float16* __restrict__ bF2,
                                              _Float16* __restrict__ whF)
{
    int id = blockIdx.x * 256 + threadIdx.x;          // 1024 blocks -> 262144
    if (id < 65536) {
        int j = id & 7, lane = (id >> 3) & 63;
        int mt = (id >> 9) & 7, ks = id >> 12;
        int m = mt * 16 + (lane & 15);
        int k = ks * 32 + ((lane >> 4) << 3) + j;
        int ph = ((m & 63) * k) & 511;
        float ang = (float)ph * (6.28318530717958647692f / 512.0f);
        bF1[id] = (_Float16)((m < 64) ? cosf(ang) : sinf(ang));
    } else if (id < 131072) {
        int id2 = id - 65536;
        int j = id2 & 7, lane = (id2 >> 3) & 63;
        int kt = (id2 >> 9) & 3, t = id2 >> 11;
        int kh = kt * 16 + (lane & 15);
        int kg = t * 32 + ((lane >> 4) << 3) + j;
        int h = kg & 511;
        int ph = (kh * h) & 511;
        float ang = (float)ph * (6.28318530717958647692f / 512.0f);
        bF2[id2] = (_Float16)((kg < 512) ? cosf(ang) : sinf(ang));
    } else {
        int idx8 = id - 131072;                       // 0..131071, 8 halfs each
        int lane = idx8 & 63;
        int f = ((idx8 >> 6) & 15) * 16 + (lane & 15);
        int k = (idx8 >> 10) * 32 + ((lane >> 4) << 3);
        const float* wp = fc_w + (size_t)f * 4096 + k;
        float4 f0 = *(const float4*)wp;
        float4 f1 = *(const float4*)(wp + 4);
        half8 o;
        o[0] = (_Float16)(f0.x * 16.0f);
        o[1] = (_Float16)(f0.y * 16.0f);
        o[2] = (_Float16)(f0.z * 16.0f);
        o[3] = (_Float16)(f0.w * 16.0f);
        o[4] = (_Float16)(f1.x * 16.0f);
        o[5] = (_Float16)(f1.y * 16.0f);
        o[6] = (_Float16)(f1.z * 16.0f);
        o[7] = (_Float16)(f1.w * 16.0f);
        *(half8*)(whF + (size_t)idx8 * 8) = o;
    }
}

// ---------------------------------------------------------------------------
// K1: gray + w-FFT.  grid (32 h-tiles, 32 b), 256 thr, 16.6 KB LDS -> 4 blk/CU.
// Output PF in k2's B-fragment order:
//  PF[b][t32][ni4][lane64][j8] = B2[kw=ni*16+(lane&15)][kglob=t*32+(lane>>4)*8+j]
//  where B2[kw,k<512]=Pc[kw][k], B2[kw,k>=512]=-Ps[kw][k-512].
// ---------------------------------------------------------------------------
__global__ __launch_bounds__(256) void k1(const float* __restrict__ x,
                                          const _Float16* __restrict__ bF1,
                                          _Float16* __restrict__ PF)
{
    __shared__ _Float16 g[16][520];
    int h0 = blockIdx.x * 16;
    int b  = blockIdx.y;
    int t  = threadIdx.x;
    const float* xb = x + (size_t)b * 3 * HW_;

    for (int i = 0; i < 8; ++i) {                     // 16 rows x 128 float4
        int slot = t + i * 256;
        int hh = slot >> 7, w4 = slot & 127;
        const float* p = xb + (size_t)(h0 + hh) * 512 + w4 * 4;
        float4 r  = *(const float4*)p;
        float4 gg = *(const float4*)(p + HW_);
        float4 bb = *(const float4*)(p + 2 * HW_);
        half4 o;
        o.x = (_Float16)(0.299f * r.x + 0.587f * gg.x + 0.114f * bb.x);
        o.y = (_Float16)(0.299f * r.y + 0.587f * gg.y + 0.114f * bb.y);
        o.z = (_Float16)(0.299f * r.z + 0.587f * gg.z + 0.114f * bb.z);
        o.w = (_Float16)(0.299f * r.w + 0.587f * gg.w + 0.114f * bb.w);
        *(half4*)&g[hh][w4 * 4] = o;
    }
    __syncthreads();

    int lane = t & 63, wv = t >> 6, l15 = lane & 15, quad = lane >> 4;
    f32x4 acc[2];
    acc[0] = (f32x4){0.f, 0.f, 0.f, 0.f};
    acc[1] = (f32x4){0.f, 0.f, 0.f, 0.f};

    for (int k0 = 0; k0 < 512; k0 += 32) {
        half8 bv = *(const half8*)&g[l15][k0 + quad * 8];
        for (int mi = 0; mi < 2; ++mi) {
            half8 a = *(const half8*)(bF1 +
                (size_t)(((k0 >> 5) * 8 + wv * 2 + mi) * 64 + lane) * 8);
            acc[mi] = __builtin_amdgcn_mfma_f32_16x16x32_f16(a, bv, acc[mi], 0, 0, 0);
        }
    }

    _Float16* Pb = PF + (size_t)b * 65536;
    int h = h0 + l15;
    for (int mi = 0; mi < 2; ++mi)
        for (int r = 0; r < 4; ++r) {
            int m = wv * 32 + mi * 16 + quad * 4 + r;
            float v = acc[mi][r];
            int m64 = m & 63;
            int tt  = (m < 64) ? (h >> 5) : 16 + (h >> 5);
            if (m >= 64) v = -v;                      // fold -sin
            int lp = (m64 & 15) | (((h >> 3) & 3) << 4);
            Pb[(size_t)((tt * 4 + (m64 >> 4)) * 64 + lp) * 8 + (h & 7)] = (_Float16)v;
        }
}

// ---------------------------------------------------------------------------
// K2: h-FFT.  grid (2, 32), 256 thr = 4 waves: (khtile = bx*2+(wv&1), K-half).
// Output XF in k3's A-fragment order:
//  XF[t128][bt2][lane64][j8] = X[b=bt*16+(lane&15)][k=t*32+(lane>>4)*8+j] / 16
// ---------------------------------------------------------------------------
__global__ __launch_bounds__(256) void k2(const _Float16* __restrict__ bF2,
                                          const _Float16* __restrict__ PF,
                                          _Float16* __restrict__ XF)
{
    __shared__ float red[2][64][17];                  // padded: conflict-free
    int b = blockIdx.y;
    int lane = threadIdx.x & 63, wv = threadIdx.x >> 6;
    int l15 = lane & 15, quad = lane >> 4;
    int khtile = blockIdx.x * 2 + (wv & 1);
    int khalf  = wv >> 1;

    const _Float16* Pb = PF + (size_t)b * 65536;
    f32x4 acc[4];
    for (int i = 0; i < 4; ++i) acc[i] = (f32x4){0.f, 0.f, 0.f, 0.f};

    int t0 = khalf * 16;
    for (int tt = t0; tt < t0 + 16; ++tt) {
        half8 a = *(const half8*)(bF2 + (size_t)((tt * 4 + khtile) * 64 + lane) * 8);
        for (int ni = 0; ni < 4; ++ni) {
            half8 bv = *(const half8*)(Pb + (size_t)((tt * 4 + ni) * 64 + lane) * 8);
            acc[ni] = __builtin_amdgcn_mfma_f32_16x16x32_f16(a, bv, acc[ni], 0, 0, 0);
        }
    }

    if (khalf)
        for (int ni = 0; ni < 4; ++ni)
            for (int r = 0; r < 4; ++r)
                red[wv & 1][lane][ni * 4 + r] = acc[ni][r];
    __syncthreads();
    if (!khalf)
        for (int ni = 0; ni < 4; ++ni)
            for (int r = 0; r < 4; ++r) {
                float v = acc[ni][r] + red[wv][lane][ni * 4 + r];
                int kh = khtile * 16 + quad * 4 + r;
                int kw = ni * 16 + l15;
                int k  = kh * 64 + kw;
                int lp = (b & 15) | (((k >> 3) & 3) << 4);
                XF[(size_t)(((k >> 5) * 2 + (b >> 4)) * 64 + lp) * 8 + (k & 7)] =
                    (_Float16)(v * 0.0625f);
            }
}

// ---------------------------------------------------------------------------
// K3: FC.  grid (16 f-tiles), 512 thr = 8 waves splitting K=4096, LDS reduce.
// No atomics, no pre-memset of out.
// ---------------------------------------------------------------------------
__global__ __launch_bounds__(512) void k3(const _Float16* __restrict__ XF,
                                          const _Float16* __restrict__ whF,
                                          const float* __restrict__ fc_b,
                                          float* __restrict__ out)
{
    __shared__ float red[8][64][9];                   // padded: conflict-free
    int nb = blockIdx.x;
    int tid = threadIdx.x;
    int lane = tid & 63, wv = tid >> 6;

    f32x4 acc[2];
    acc[0] = (f32x4){0.f, 0.f, 0.f, 0.f};
    acc[1] = (f32x4){0.f, 0.f, 0.f, 0.f};

    for (int it = 0; it < 16; ++it) {
        int tt = wv * 16 + it;                        // k>>5
        half8 a0 = *(const half8*)(XF + (size_t)((tt * 2 + 0) * 64 + lane) * 8);
        half8 a1 = *(const half8*)(XF + (size_t)((tt * 2 + 1) * 64 + lane) * 8);
        half8 bv = *(const half8*)(whF + (size_t)((tt * 16 + nb) * 64 + lane) * 8);
        acc[0] = __builtin_amdgcn_mfma_f32_16x16x32_f16(a0, bv, acc[0], 0, 0, 0);
        acc[1] = __builtin_amdgcn_mfma_f32_16x16x32_f16(a1, bv, acc[1], 0, 0, 0);
    }

    for (int j = 0; j < 8; ++j)
        red[wv][lane][j] = acc[j >> 2][j & 3];
    __syncthreads();

    int lp = tid >> 3, j = tid & 7;                   // 512 outputs per block
    float s = 0.f;
    for (int w = 0; w < 8; ++w) s += red[w][lp][j];
    int batch = (j >> 2) * 16 + (lp >> 4) * 4 + (j & 3);
    int f = nb * 16 + (lp & 15);
    out[batch * 256 + f] = s + fc_b[f];
}

// ---------------------------------------------------------------------------
extern "C" void kernel_launch(void* const* d_in, const int* in_sizes, int n_in,
                              void* d_out, int out_size, void* d_ws, size_t ws_size,
                              hipStream_t stream) {
    const float* x    = (const float*)d_in[0];
    const float* fc_w = (const float*)d_in[1];
    const float* fc_b = (const float*)d_in[2];
    float* out = (float*)d_out;

    char* ws = (char*)d_ws;
    _Float16* bF1 = (_Float16*)(ws);                 // 131072 B
    _Float16* bF2 = (_Float16*)(ws + 131072);        // 131072 B
    _Float16* whF = (_Float16*)(ws + 262144);        // 2097152 B
    _Float16* PF  = (_Float16*)(ws + 2359296);       // 4194304 B
    _Float16* XF  = (_Float16*)(ws + 6553600);       // 262144 B  -> ~6.5 MiB

    k_prep<<<1024, 256, 0, stream>>>(fc_w, bF1, bF2, whF);
    k1<<<dim3(32, 32), 256, 0, stream>>>(x, bF1, PF);
    k2<<<dim3(2, 32), 256, 0, stream>>>(bF2, PF, XF);
    k3<<<16, 512, 0, stream>>>(XF, whF, fc_b, out);
}

// Round 2
// 171.205 us; speedup vs baseline: 1.1046x; 1.0418x over previous
//
#include <hip/hip_runtime.h>

#define HW_ (512 * 512)
#define TWOPI_512 0.01227184630308513f   // 2*pi/512

typedef __attribute__((ext_vector_type(8))) _Float16 half8;
typedef __attribute__((ext_vector_type(4))) _Float16 half4;
typedef __attribute__((ext_vector_type(4))) float    f32x4;

// ---------------------------------------------------------------------------
// K1: gray + w-FFT with INLINE basis (no k_prep, no bF1 table).
// grid (33, 32): bx<32 = h-tile, bx==32 = whF prep block (pid = by).
// Output PF in k2's B-fragment order:
//  PF[b][t32][ni4][lane64][j8] = B2[kw][kglob], B2 = (C | -S).
// Also writes whF[t128][ft16][lane64][j8] = fc_w * 16 (f16), consumed by k3.
// ---------------------------------------------------------------------------
template<bool SIN>
__device__ __forceinline__ void k1_loop(const _Float16 (*g)[520],
                                        int l15, int quad, int mk0, int mk1,
                                        f32x4& acc0, f32x4& acc1)
{
    for (int k0 = 0; k0 < 512; k0 += 32) {
        int kc = k0 + quad * 8;
        half8 bv = *(const half8*)&g[l15][kc];
        half8 a0, a1;
#pragma unroll
        for (int j = 0; j < 8; ++j) {
            int k = kc + j;
            float ang0 = (float)(__mul24(mk0, k) & 511) * TWOPI_512;
            float ang1 = (float)(__mul24(mk1, k) & 511) * TWOPI_512;
            a0[j] = (_Float16)(SIN ? __sinf(ang0) : __cosf(ang0));
            a1[j] = (_Float16)(SIN ? __sinf(ang1) : __cosf(ang1));
        }
        acc0 = __builtin_amdgcn_mfma_f32_16x16x32_f16(a0, bv, acc0, 0, 0, 0);
        acc1 = __builtin_amdgcn_mfma_f32_16x16x32_f16(a1, bv, acc1, 0, 0, 0);
    }
}

__global__ __launch_bounds__(256) void k1(const float* __restrict__ x,
                                          const float* __restrict__ fc_w,
                                          _Float16* __restrict__ PF,
                                          _Float16* __restrict__ whF)
{
    __shared__ _Float16 g[16][520];
    int t = threadIdx.x;

    if (blockIdx.x == 32) {                     // ---- whF prep (32 blocks) ----
        int pid = blockIdx.y;
        for (int it = 0; it < 16; ++it) {
            int idx8 = pid * 4096 + it * 256 + t;
            int lane = idx8 & 63;
            int f = ((idx8 >> 6) & 15) * 16 + (lane & 15);
            int k = (idx8 >> 10) * 32 + ((lane >> 4) << 3);
            const float* wp = fc_w + (size_t)f * 4096 + k;
            float4 f0 = *(const float4*)wp;
            float4 f1 = *(const float4*)(wp + 4);
            half8 o;
            o[0] = (_Float16)(f0.x * 16.0f);
            o[1] = (_Float16)(f0.y * 16.0f);
            o[2] = (_Float16)(f0.z * 16.0f);
            o[3] = (_Float16)(f0.w * 16.0f);
            o[4] = (_Float16)(f1.x * 16.0f);
            o[5] = (_Float16)(f1.y * 16.0f);
            o[6] = (_Float16)(f1.z * 16.0f);
            o[7] = (_Float16)(f1.w * 16.0f);
            *(half8*)(whF + (size_t)idx8 * 8) = o;
        }
        return;
    }

    int h0 = blockIdx.x * 16;
    int b  = blockIdx.y;
    const float* xb = x + (size_t)b * 3 * HW_;

    for (int i = 0; i < 8; ++i) {               // stage gray slab 16 x 512
        int slot = t + i * 256;
        int hh = slot >> 7, w4 = slot & 127;
        const float* p = xb + (size_t)(h0 + hh) * 512 + w4 * 4;
        float4 r  = *(const float4*)p;
        float4 gg = *(const float4*)(p + HW_);
        float4 bb = *(const float4*)(p + 2 * HW_);
        half4 o;
        o.x = (_Float16)(0.299f * r.x + 0.587f * gg.x + 0.114f * bb.x);
        o.y = (_Float16)(0.299f * r.y + 0.587f * gg.y + 0.114f * bb.y);
        o.z = (_Float16)(0.299f * r.z + 0.587f * gg.z + 0.114f * bb.z);
        o.w = (_Float16)(0.299f * r.w + 0.587f * gg.w + 0.114f * bb.w);
        *(half4*)&g[hh][w4 * 4] = o;
    }
    __syncthreads();

    int lane = t & 63, wv = t >> 6, l15 = lane & 15, quad = lane >> 4;
    int mk0 = (wv * 32 + l15) & 63;             // row of a0 (mi=0)
    int mk1 = (wv * 32 + 16 + l15) & 63;        // row of a1 (mi=1)

    f32x4 acc[2];
    acc[0] = (f32x4){0.f, 0.f, 0.f, 0.f};
    acc[1] = (f32x4){0.f, 0.f, 0.f, 0.f};

    if (wv >= 2) k1_loop<true >(g, l15, quad, mk0, mk1, acc[0], acc[1]);
    else         k1_loop<false>(g, l15, quad, mk0, mk1, acc[0], acc[1]);

    _Float16* Pb = PF + (size_t)b * 65536;
    int h = h0 + l15;
    for (int mi = 0; mi < 2; ++mi)
        for (int r = 0; r < 4; ++r) {
            int m = wv * 32 + mi * 16 + quad * 4 + r;
            float v = acc[mi][r];
            int m64 = m & 63;
            int tt  = (m < 64) ? (h >> 5) : 16 + (h >> 5);
            if (m >= 64) v = -v;                // fold -sin
            int lp = (m64 & 15) | (((h >> 3) & 3) << 4);
            Pb[(size_t)((tt * 4 + (m64 >> 4)) * 64 + lp) * 8 + (h & 7)] = (_Float16)v;
        }
}

// ---------------------------------------------------------------------------
// K2: h-FFT, inline basis.  grid (4 khtiles, 32 b), 4 waves split K 4-ways,
// LDS reduce.  Output XF in k3's A-fragment order:
//  XF[t128][bt2][lane64][j8] = X[b][k] / 16
// ---------------------------------------------------------------------------
template<bool SIN>
__device__ __forceinline__ void k2_loop(const _Float16* __restrict__ Pb,
                                        int t0, int kh, int quad, int lane,
                                        f32x4* acc)
{
    for (int it = 0; it < 8; ++it) {
        int tt = t0 + it;
        int kgb = tt * 32 + quad * 8;
        half8 a;
#pragma unroll
        for (int j = 0; j < 8; ++j) {
            int h = (kgb + j) & 511;
            float ang = (float)(__mul24(kh, h) & 511) * TWOPI_512;
            a[j] = (_Float16)(SIN ? __sinf(ang) : __cosf(ang));
        }
        for (int ni = 0; ni < 4; ++ni) {
            half8 bv = *(const half8*)(Pb + (size_t)((tt * 4 + ni) * 64 + lane) * 8);
            acc[ni] = __builtin_amdgcn_mfma_f32_16x16x32_f16(a, bv, acc[ni], 0, 0, 0);
        }
    }
}

__global__ __launch_bounds__(256) void k2(const _Float16* __restrict__ PF,
                                          _Float16* __restrict__ XF)
{
    __shared__ float red[3][64][17];
    int b  = blockIdx.y;
    int bx = blockIdx.x;                        // kh tile
    int lane = threadIdx.x & 63, wv = threadIdx.x >> 6;
    int l15 = lane & 15, quad = lane >> 4;
    int kh = bx * 16 + l15;

    const _Float16* Pb = PF + (size_t)b * 65536;
    f32x4 acc[4];
    for (int i = 0; i < 4; ++i) acc[i] = (f32x4){0.f, 0.f, 0.f, 0.f};

    if (wv >= 2) k2_loop<true >(Pb, wv * 8, kh, quad, lane, acc);  // tt 16..31: sin
    else         k2_loop<false>(Pb, wv * 8, kh, quad, lane, acc);  // tt  0..15: cos

    if (wv)
        for (int ni = 0; ni < 4; ++ni)
            for (int r = 0; r < 4; ++r)
                red[wv - 1][lane][ni * 4 + r] = acc[ni][r];
    __syncthreads();
    if (!wv)
        for (int ni = 0; ni < 4; ++ni)
            for (int r = 0; r < 4; ++r) {
                float v = acc[ni][r] + red[0][lane][ni * 4 + r]
                                     + red[1][lane][ni * 4 + r]
                                     + red[2][lane][ni * 4 + r];
                int khr = bx * 16 + quad * 4 + r;
                int kw  = ni * 16 + l15;
                int k   = khr * 64 + kw;
                int lp  = (b & 15) | (((k >> 3) & 3) << 4);
                XF[(size_t)(((k >> 5) * 2 + (b >> 4)) * 64 + lp) * 8 + (k & 7)] =
                    (_Float16)(v * 0.0625f);
            }
}

// ---------------------------------------------------------------------------
// K3: FC.  grid (16 f-tiles), 512 thr = 8 waves splitting K=4096, LDS reduce.
// ---------------------------------------------------------------------------
__global__ __launch_bounds__(512) void k3(const _Float16* __restrict__ XF,
                                          const _Float16* __restrict__ whF,
                                          const float* __restrict__ fc_b,
                                          float* __restrict__ out)
{
    __shared__ float red[8][64][9];
    int nb = blockIdx.x;
    int tid = threadIdx.x;
    int lane = tid & 63, wv = tid >> 6;

    f32x4 acc[2];
    acc[0] = (f32x4){0.f, 0.f, 0.f, 0.f};
    acc[1] = (f32x4){0.f, 0.f, 0.f, 0.f};

    for (int it = 0; it < 16; ++it) {
        int tt = wv * 16 + it;                  // k>>5
        half8 a0 = *(const half8*)(XF + (size_t)((tt * 2 + 0) * 64 + lane) * 8);
        half8 a1 = *(const half8*)(XF + (size_t)((tt * 2 + 1) * 64 + lane) * 8);
        half8 bv = *(const half8*)(whF + (size_t)((tt * 16 + nb) * 64 + lane) * 8);
        acc[0] = __builtin_amdgcn_mfma_f32_16x16x32_f16(a0, bv, acc[0], 0, 0, 0);
        acc[1] = __builtin_amdgcn_mfma_f32_16x16x32_f16(a1, bv, acc[1], 0, 0, 0);
    }

    for (int j = 0; j < 8; ++j)
        red[wv][lane][j] = acc[j >> 2][j & 3];
    __syncthreads();

    int lp = tid >> 3, j = tid & 7;             // 512 outputs per block
    float s = 0.f;
    for (int w = 0; w < 8; ++w) s += red[w][lp][j];
    int batch = (j >> 2) * 16 + (lp >> 4) * 4 + (j & 3);
    int f = nb * 16 + (lp & 15);
    out[batch * 256 + f] = s + fc_b[f];
}

// ---------------------------------------------------------------------------
extern "C" void kernel_launch(void* const* d_in, const int* in_sizes, int n_in,
                              void* d_out, int out_size, void* d_ws, size_t ws_size,
                              hipStream_t stream) {
    const float* x    = (const float*)d_in[0];
    const float* fc_w = (const float*)d_in[1];
    const float* fc_b = (const float*)d_in[2];
    float* out = (float*)d_out;

    char* ws = (char*)d_ws;
    _Float16* PF  = (_Float16*)(ws);                 // 4194304 B
    _Float16* XF  = (_Float16*)(ws + 4194304);       //  262144 B
    _Float16* whF = (_Float16*)(ws + 4456448);       // 2097152 B -> ~6.3 MiB

    k1<<<dim3(33, 32), 256, 0, stream>>>(x, fc_w, PF, whF);
    k2<<<dim3(4, 32),  256, 0, stream>>>(PF, XF);
    k3<<<16, 512, 0, stream>>>(XF, whF, fc_b, out);
}

// Round 3
// 162.555 us; speedup vs baseline: 1.1634x; 1.0532x over previous
//
#include <hip/hip_runtime.h>

#define HW_ (512 * 512)
#define TWOPI_512 0.01227184630308513f   // 2*pi/512

typedef __attribute__((ext_vector_type(8))) _Float16 half8;
typedef __attribute__((ext_vector_type(4))) _Float16 half4;
typedef __attribute__((ext_vector_type(4))) float    f32x4;

// ---------------------------------------------------------------------------
// K1: gray + w-FFT, inline basis via angle-addition rotors.
// grid (33, 32): bx<32 = h-tile, bx==32 = whF prep block (pid = by).
// Output PF in k2's B-fragment order:
//  PF[b][t32][ni4][lane64][j8] = B2[kw][kglob], B2 = (C | -S).
// whF[t128][ft16][lane64][j8] = fc_w * 16 (f16), consumed by k3.
// ---------------------------------------------------------------------------
template<bool SIN>
__device__ __forceinline__ void k1_loop(const _Float16 (*g)[520],
                                        int l15, int quad, int mk0, int mk1,
                                        f32x4& acc0, f32x4& acc1)
{
    // rotors: cos/sin(theta_m * j), j=0..7, exact integer phase
    float c0r[8], s0r[8], c1r[8], s1r[8];
#pragma unroll
    for (int j = 0; j < 8; ++j) {
        float a0 = (float)((mk0 * j) & 511) * TWOPI_512;
        float a1 = (float)((mk1 * j) & 511) * TWOPI_512;
        c0r[j] = __cosf(a0); s0r[j] = __sinf(a0);
        c1r[j] = __cosf(a1); s1r[j] = __sinf(a1);
    }
    for (int k0 = 0; k0 < 512; k0 += 32) {
        int kc = k0 + quad * 8;
        half8 bv = *(const half8*)&g[l15][kc];
        float b0 = (float)((mk0 * kc) & 511) * TWOPI_512;
        float b1 = (float)((mk1 * kc) & 511) * TWOPI_512;
        float cb0 = __cosf(b0), sb0 = __sinf(b0);
        float cb1 = __cosf(b1), sb1 = __sinf(b1);
        half8 a0v, a1v;
#pragma unroll
        for (int j = 0; j < 8; ++j) {
            float v0 = SIN ? (sb0 * c0r[j] + cb0 * s0r[j])
                           : (cb0 * c0r[j] - sb0 * s0r[j]);
            float v1 = SIN ? (sb1 * c1r[j] + cb1 * s1r[j])
                           : (cb1 * c1r[j] - sb1 * s1r[j]);
            a0v[j] = (_Float16)v0;
            a1v[j] = (_Float16)v1;
        }
        acc0 = __builtin_amdgcn_mfma_f32_16x16x32_f16(a0v, bv, acc0, 0, 0, 0);
        acc1 = __builtin_amdgcn_mfma_f32_16x16x32_f16(a1v, bv, acc1, 0, 0, 0);
    }
}

__global__ __launch_bounds__(256) void k1(const float* __restrict__ x,
                                          const float* __restrict__ fc_w,
                                          _Float16* __restrict__ PF,
                                          _Float16* __restrict__ whF)
{
    __shared__ _Float16 g[16][520];
    int t = threadIdx.x;

    if (blockIdx.x == 32) {                     // ---- whF prep (32 blocks) ----
        int pid = blockIdx.y;
        for (int it = 0; it < 16; ++it) {
            int idx8 = pid * 4096 + it * 256 + t;
            int lane = idx8 & 63;
            int f = ((idx8 >> 6) & 15) * 16 + (lane & 15);
            int k = (idx8 >> 10) * 32 + ((lane >> 4) << 3);
            const float* wp = fc_w + (size_t)f * 4096 + k;
            float4 f0 = *(const float4*)wp;
            float4 f1 = *(const float4*)(wp + 4);
            half8 o;
            o[0] = (_Float16)(f0.x * 16.0f);
            o[1] = (_Float16)(f0.y * 16.0f);
            o[2] = (_Float16)(f0.z * 16.0f);
            o[3] = (_Float16)(f0.w * 16.0f);
            o[4] = (_Float16)(f1.x * 16.0f);
            o[5] = (_Float16)(f1.y * 16.0f);
            o[6] = (_Float16)(f1.z * 16.0f);
            o[7] = (_Float16)(f1.w * 16.0f);
            *(half8*)(whF + (size_t)idx8 * 8) = o;
        }
        return;
    }

    int h0 = blockIdx.x * 16;
    int b  = blockIdx.y;
    const float* xb = x + (size_t)b * 3 * HW_;

    for (int i = 0; i < 8; ++i) {               // stage gray slab 16 x 512
        int slot = t + i * 256;
        int hh = slot >> 7, w4 = slot & 127;
        const float* p = xb + (size_t)(h0 + hh) * 512 + w4 * 4;
        float4 r  = *(const float4*)p;
        float4 gg = *(const float4*)(p + HW_);
        float4 bb = *(const float4*)(p + 2 * HW_);
        half4 o;
        o.x = (_Float16)(0.299f * r.x + 0.587f * gg.x + 0.114f * bb.x);
        o.y = (_Float16)(0.299f * r.y + 0.587f * gg.y + 0.114f * bb.y);
        o.z = (_Float16)(0.299f * r.z + 0.587f * gg.z + 0.114f * bb.z);
        o.w = (_Float16)(0.299f * r.w + 0.587f * gg.w + 0.114f * bb.w);
        *(half4*)&g[hh][w4 * 4] = o;
    }
    __syncthreads();

    int lane = t & 63, wv = t >> 6, l15 = lane & 15, quad = lane >> 4;
    int mk0 = (wv * 32 + l15) & 63;
    int mk1 = (wv * 32 + 16 + l15) & 63;

    f32x4 acc[2];
    acc[0] = (f32x4){0.f, 0.f, 0.f, 0.f};
    acc[1] = (f32x4){0.f, 0.f, 0.f, 0.f};

    if (wv >= 2) k1_loop<true >(g, l15, quad, mk0, mk1, acc[0], acc[1]);
    else         k1_loop<false>(g, l15, quad, mk0, mk1, acc[0], acc[1]);

    _Float16* Pb = PF + (size_t)b * 65536;
    int h = h0 + l15;
    for (int mi = 0; mi < 2; ++mi)
        for (int r = 0; r < 4; ++r) {
            int m = wv * 32 + mi * 16 + quad * 4 + r;
            float v = acc[mi][r];
            int m64 = m & 63;
            int tt  = (m < 64) ? (h >> 5) : 16 + (h >> 5);
            if (m >= 64) v = -v;                // fold -sin
            int lp = (m64 & 15) | (((h >> 3) & 3) << 4);
            Pb[(size_t)((tt * 4 + (m64 >> 4)) * 64 + lp) * 8 + (h & 7)] = (_Float16)v;
        }
}

// ---------------------------------------------------------------------------
// K2: h-FFT, inline basis.  grid (4 khtiles, 32 b), 4 waves split K 4-ways,
// LDS reduce.  Output XF in k3's A-fragment order.
// ---------------------------------------------------------------------------
template<bool SIN>
__device__ __forceinline__ void k2_loop(const _Float16* __restrict__ Pb,
                                        int t0, int kh, int quad, int lane,
                                        f32x4* acc)
{
    for (int it = 0; it < 8; ++it) {
        int tt = t0 + it;
        int kgb = tt * 32 + quad * 8;
        half8 a;
#pragma unroll
        for (int j = 0; j < 8; ++j) {
            int h = (kgb + j) & 511;
            float ang = (float)(__mul24(kh, h) & 511) * TWOPI_512;
            a[j] = (_Float16)(SIN ? __sinf(ang) : __cosf(ang));
        }
        for (int ni = 0; ni < 4; ++ni) {
            half8 bv = *(const half8*)(Pb + (size_t)((tt * 4 + ni) * 64 + lane) * 8);
            acc[ni] = __builtin_amdgcn_mfma_f32_16x16x32_f16(a, bv, acc[ni], 0, 0, 0);
        }
    }
}

__global__ __launch_bounds__(256) void k2(const _Float16* __restrict__ PF,
                                          _Float16* __restrict__ XF)
{
    __shared__ float red[3][64][17];
    int b  = blockIdx.y;
    int bx = blockIdx.x;
    int lane = threadIdx.x & 63, wv = threadIdx.x >> 6;
    int l15 = lane & 15, quad = lane >> 4;
    int kh = bx * 16 + l15;

    const _Float16* Pb = PF + (size_t)b * 65536;
    f32x4 acc[4];
    for (int i = 0; i < 4; ++i) acc[i] = (f32x4){0.f, 0.f, 0.f, 0.f};

    if (wv >= 2) k2_loop<true >(Pb, wv * 8, kh, quad, lane, acc);
    else         k2_loop<false>(Pb, wv * 8, kh, quad, lane, acc);

    if (wv)
        for (int ni = 0; ni < 4; ++ni)
            for (int r = 0; r < 4; ++r)
                red[wv - 1][lane][ni * 4 + r] = acc[ni][r];
    __syncthreads();
    if (!wv)
        for (int ni = 0; ni < 4; ++ni)
            for (int r = 0; r < 4; ++r) {
                float v = acc[ni][r] + red[0][lane][ni * 4 + r]
                                     + red[1][lane][ni * 4 + r]
                                     + red[2][lane][ni * 4 + r];
                int khr = bx * 16 + quad * 4 + r;
                int kw  = ni * 16 + l15;
                int k   = khr * 64 + kw;
                int lp  = (b & 15) | (((k >> 3) & 3) << 4);
                XF[(size_t)(((k >> 5) * 2 + (b >> 4)) * 64 + lp) * 8 + (k & 7)] =
                    (_Float16)(v * 0.0625f);
            }
}

// ---------------------------------------------------------------------------
// K3: FC partials.  grid 128 = (nb = bid&15, kc = bid>>4), 8 waves over K=512.
// Writes f32 partials to wsP[kc*16+nb][batch*16+fi].  No atomics.
// ---------------------------------------------------------------------------
__global__ __launch_bounds__(512) void k3(const _Float16* __restrict__ XF,
                                          const _Float16* __restrict__ whF,
                                          float* __restrict__ wsP)
{
    __shared__ float red[8][64][9];
    int nb = blockIdx.x & 15;
    int kc = blockIdx.x >> 4;
    int tid = threadIdx.x;
    int lane = tid & 63, wv = tid >> 6;

    f32x4 acc[2];
    acc[0] = (f32x4){0.f, 0.f, 0.f, 0.f};
    acc[1] = (f32x4){0.f, 0.f, 0.f, 0.f};

    for (int it = 0; it < 2; ++it) {
        int tt = kc * 16 + wv * 2 + it;         // k>>5
        half8 a0 = *(const half8*)(XF + (size_t)((tt * 2 + 0) * 64 + lane) * 8);
        half8 a1 = *(const half8*)(XF + (size_t)((tt * 2 + 1) * 64 + lane) * 8);
        half8 bv = *(const half8*)(whF + (size_t)((tt * 16 + nb) * 64 + lane) * 8);
        acc[0] = __builtin_amdgcn_mfma_f32_16x16x32_f16(a0, bv, acc[0], 0, 0, 0);
        acc[1] = __builtin_amdgcn_mfma_f32_16x16x32_f16(a1, bv, acc[1], 0, 0, 0);
    }

    for (int j = 0; j < 8; ++j)
        red[wv][lane][j] = acc[j >> 2][j & 3];
    __syncthreads();

    int lp = tid >> 3, j = tid & 7;             // 512 partials per block
    float s = 0.f;
    for (int w = 0; w < 8; ++w) s += red[w][lp][j];
    int batch = (j >> 2) * 16 + (lp >> 4) * 4 + (j & 3);
    int fi = lp & 15;
    wsP[(size_t)blockIdx.x * 512 + batch * 16 + fi] = s;
}

// ---------------------------------------------------------------------------
// K4: reduce 8 K-chunks + bias.  32 blocks x 256 thr = one thread per output.
// ---------------------------------------------------------------------------
__global__ __launch_bounds__(256) void k4(const float* __restrict__ wsP,
                                          const float* __restrict__ fc_b,
                                          float* __restrict__ out)
{
    int gid = blockIdx.x * 256 + threadIdx.x;   // 8192 = 32 b x 256 f
    int m = gid >> 8, f = gid & 255;
    int nb = f >> 4, fi = f & 15;
    float s = fc_b[f];
    for (int kc = 0; kc < 8; ++kc)
        s += wsP[(size_t)(kc * 16 + nb) * 512 + m * 16 + fi];
    out[gid] = s;
}

// ---------------------------------------------------------------------------
extern "C" void kernel_launch(void* const* d_in, const int* in_sizes, int n_in,
                              void* d_out, int out_size, void* d_ws, size_t ws_size,
                              hipStream_t stream) {
    const float* x    = (const float*)d_in[0];
    const float* fc_w = (const float*)d_in[1];
    const float* fc_b = (const float*)d_in[2];
    float* out = (float*)d_out;

    char* ws = (char*)d_ws;
    _Float16* PF  = (_Float16*)(ws);                 // 4194304 B
    _Float16* XF  = (_Float16*)(ws + 4194304);       //  262144 B
    _Float16* whF = (_Float16*)(ws + 4456448);       // 2097152 B
    float*    wsP = (float*)   (ws + 6553600);       //  262144 B -> ~6.8 MiB

    k1<<<dim3(33, 32), 256, 0, stream>>>(x, fc_w, PF, whF);
    k2<<<dim3(4, 32),  256, 0, stream>>>(PF, XF);
    k3<<<128, 512, 0, stream>>>(XF, whF, wsP);
    k4<<<32, 256, 0, stream>>>(wsP, fc_b, out);
}

// Round 4
// 162.530 us; speedup vs baseline: 1.1635x; 1.0001x over previous
//
#include <hip/hip_runtime.h>

#define HW_ (512 * 512)
#define TWOPI_512 0.01227184630308513f   // 2*pi/512

typedef __attribute__((ext_vector_type(8))) _Float16 half8;
typedef __attribute__((ext_vector_type(4))) _Float16 half4;
typedef __attribute__((ext_vector_type(4))) float    f32x4;

// ---------------------------------------------------------------------------
// K1: gray + w-FFT, inline basis via angle-addition rotors.
// grid (33, 32): bx<32 = h-tile, bx==32 = whF prep block (pid = by).
// Output PF in k2's B-fragment order:
//  PF[b][t32][ni4][lane64][j8] = B2[kw][kglob], B2 = (C | -S).
// whF[t128][ft16][lane64][j8] = fc_w * 16 (f16), consumed by k3.
// ---------------------------------------------------------------------------
template<bool SIN>
__device__ __forceinline__ void k1_loop(const _Float16 (*g)[520],
                                        int l15, int quad, int mk0, int mk1,
                                        f32x4& acc0, f32x4& acc1)
{
    // rotors: cos/sin(theta_m * j), j=0..7, exact integer phase
    float c0r[8], s0r[8], c1r[8], s1r[8];
#pragma unroll
    for (int j = 0; j < 8; ++j) {
        float a0 = (float)((mk0 * j) & 511) * TWOPI_512;
        float a1 = (float)((mk1 * j) & 511) * TWOPI_512;
        c0r[j] = __cosf(a0); s0r[j] = __sinf(a0);
        c1r[j] = __cosf(a1); s1r[j] = __sinf(a1);
    }
    for (int k0 = 0; k0 < 512; k0 += 32) {
        int kc = k0 + quad * 8;
        half8 bv = *(const half8*)&g[l15][kc];
        float b0 = (float)((mk0 * kc) & 511) * TWOPI_512;
        float b1 = (float)((mk1 * kc) & 511) * TWOPI_512;
        float cb0 = __cosf(b0), sb0 = __sinf(b0);
        float cb1 = __cosf(b1), sb1 = __sinf(b1);
        half8 a0v, a1v;
#pragma unroll
        for (int j = 0; j < 8; ++j) {
            float v0 = SIN ? (sb0 * c0r[j] + cb0 * s0r[j])
                           : (cb0 * c0r[j] - sb0 * s0r[j]);
            float v1 = SIN ? (sb1 * c1r[j] + cb1 * s1r[j])
                           : (cb1 * c1r[j] - sb1 * s1r[j]);
            a0v[j] = (_Float16)v0;
            a1v[j] = (_Float16)v1;
        }
        acc0 = __builtin_amdgcn_mfma_f32_16x16x32_f16(a0v, bv, acc0, 0, 0, 0);
        acc1 = __builtin_amdgcn_mfma_f32_16x16x32_f16(a1v, bv, acc1, 0, 0, 0);
    }
}

__global__ __launch_bounds__(256) void k1(const float* __restrict__ x,
                                          const float* __restrict__ fc_w,
                                          _Float16* __restrict__ PF,
                                          _Float16* __restrict__ whF)
{
    __shared__ _Float16 g[16][520];
    int t = threadIdx.x;

    if (blockIdx.x == 32) {                     // ---- whF prep (32 blocks) ----
        int pid = blockIdx.y;
        for (int it = 0; it < 16; ++it) {
            int idx8 = pid * 4096 + it * 256 + t;
            int lane = idx8 & 63;
            int f = ((idx8 >> 6) & 15) * 16 + (lane & 15);
            int k = (idx8 >> 10) * 32 + ((lane >> 4) << 3);
            const float* wp = fc_w + (size_t)f * 4096 + k;
            float4 f0 = *(const float4*)wp;
            float4 f1 = *(const float4*)(wp + 4);
            half8 o;
            o[0] = (_Float16)(f0.x * 16.0f);
            o[1] = (_Float16)(f0.y * 16.0f);
            o[2] = (_Float16)(f0.z * 16.0f);
            o[3] = (_Float16)(f0.w * 16.0f);
            o[4] = (_Float16)(f1.x * 16.0f);
            o[5] = (_Float16)(f1.y * 16.0f);
            o[6] = (_Float16)(f1.z * 16.0f);
            o[7] = (_Float16)(f1.w * 16.0f);
            *(half8*)(whF + (size_t)idx8 * 8) = o;
        }
        return;
    }

    int h0 = blockIdx.x * 16;
    int b  = blockIdx.y;
    const float* xb = x + (size_t)b * 3 * HW_;

    for (int i = 0; i < 8; ++i) {               // stage gray slab 16 x 512
        int slot = t + i * 256;
        int hh = slot >> 7, w4 = slot & 127;
        const float* p = xb + (size_t)(h0 + hh) * 512 + w4 * 4;
        float4 r  = *(const float4*)p;
        float4 gg = *(const float4*)(p + HW_);
        float4 bb = *(const float4*)(p + 2 * HW_);
        half4 o;
        o.x = (_Float16)(0.299f * r.x + 0.587f * gg.x + 0.114f * bb.x);
        o.y = (_Float16)(0.299f * r.y + 0.587f * gg.y + 0.114f * bb.y);
        o.z = (_Float16)(0.299f * r.z + 0.587f * gg.z + 0.114f * bb.z);
        o.w = (_Float16)(0.299f * r.w + 0.587f * gg.w + 0.114f * bb.w);
        *(half4*)&g[hh][w4 * 4] = o;
    }
    __syncthreads();

    int lane = t & 63, wv = t >> 6, l15 = lane & 15, quad = lane >> 4;
    int mk0 = (wv * 32 + l15) & 63;
    int mk1 = (wv * 32 + 16 + l15) & 63;

    f32x4 acc[2];
    acc[0] = (f32x4){0.f, 0.f, 0.f, 0.f};
    acc[1] = (f32x4){0.f, 0.f, 0.f, 0.f};

    if (wv >= 2) k1_loop<true >(g, l15, quad, mk0, mk1, acc[0], acc[1]);
    else         k1_loop<false>(g, l15, quad, mk0, mk1, acc[0], acc[1]);

    _Float16* Pb = PF + (size_t)b * 65536;
    int h = h0 + l15;
    for (int mi = 0; mi < 2; ++mi)
        for (int r = 0; r < 4; ++r) {
            int m = wv * 32 + mi * 16 + quad * 4 + r;
            float v = acc[mi][r];
            int m64 = m & 63;
            int tt  = (m < 64) ? (h >> 5) : 16 + (h >> 5);
            if (m >= 64) v = -v;                // fold -sin
            int lp = (m64 & 15) | (((h >> 3) & 3) << 4);
            Pb[(size_t)((tt * 4 + (m64 >> 4)) * 64 + lp) * 8 + (h & 7)] = (_Float16)v;
        }
}

// ---------------------------------------------------------------------------
// K2: h-FFT, inline basis.  grid (4 khtiles, 32 b), 4 waves split K 4-ways,
// LDS reduce.  Output XF in k3's A-fragment order.
// ---------------------------------------------------------------------------
template<bool SIN>
__device__ __forceinline__ void k2_loop(const _Float16* __restrict__ Pb,
                                        int t0, int kh, int quad, int lane,
                                        f32x4* acc)
{
    for (int it = 0; it < 8; ++it) {
        int tt = t0 + it;
        int kgb = tt * 32 + quad * 8;
        half8 a;
#pragma unroll
        for (int j = 0; j < 8; ++j) {
            int h = (kgb + j) & 511;
            float ang = (float)(__mul24(kh, h) & 511) * TWOPI_512;
            a[j] = (_Float16)(SIN ? __sinf(ang) : __cosf(ang));
        }
        for (int ni = 0; ni < 4; ++ni) {
            half8 bv = *(const half8*)(Pb + (size_t)((tt * 4 + ni) * 64 + lane) * 8);
            acc[ni] = __builtin_amdgcn_mfma_f32_16x16x32_f16(a, bv, acc[ni], 0, 0, 0);
        }
    }
}

__global__ __launch_bounds__(256) void k2(const _Float16* __restrict__ PF,
                                          _Float16* __restrict__ XF)
{
    __shared__ float red[3][64][17];
    int b  = blockIdx.y;
    int bx = blockIdx.x;
    int lane = threadIdx.x & 63, wv = threadIdx.x >> 6;
    int l15 = lane & 15, quad = lane >> 4;
    int kh = bx * 16 + l15;

    const _Float16* Pb = PF + (size_t)b * 65536;
    f32x4 acc[4];
    for (int i = 0; i < 4; ++i) acc[i] = (f32x4){0.f, 0.f, 0.f, 0.f};

    if (wv >= 2) k2_loop<true >(Pb, wv * 8, kh, quad, lane, acc);
    else         k2_loop<false>(Pb, wv * 8, kh, quad, lane, acc);

    if (wv)
        for (int ni = 0; ni < 4; ++ni)
            for (int r = 0; r < 4; ++r)
                red[wv - 1][lane][ni * 4 + r] = acc[ni][r];
    __syncthreads();
    if (!wv)
        for (int ni = 0; ni < 4; ++ni)
            for (int r = 0; r < 4; ++r) {
                float v = acc[ni][r] + red[0][lane][ni * 4 + r]
                                     + red[1][lane][ni * 4 + r]
                                     + red[2][lane][ni * 4 + r];
                int khr = bx * 16 + quad * 4 + r;
                int kw  = ni * 16 + l15;
                int k   = khr * 64 + kw;
                int lp  = (b & 15) | (((k >> 3) & 3) << 4);
                XF[(size_t)(((k >> 5) * 2 + (b >> 4)) * 64 + lp) * 8 + (k & 7)] =
                    (_Float16)(v * 0.0625f);
            }
}

// ---------------------------------------------------------------------------
// K3: FC with bias, no partials, no k4.
// grid 32 = (nb = bid&15 feature tile, bt = bid>>4 batch tile).
// 512 thr = 8 waves splitting K=4096 (16 tt each), LDS reduce, write out.
// ---------------------------------------------------------------------------
__global__ __launch_bounds__(512) void k3(const _Float16* __restrict__ XF,
                                          const _Float16* __restrict__ whF,
                                          const float* __restrict__ fc_b,
                                          float* __restrict__ out)
{
    __shared__ float red[8][64][5];              // pad 5: 2-way max (free)
    int nb = blockIdx.x & 15;
    int bt = blockIdx.x >> 4;
    int tid = threadIdx.x;
    int lane = tid & 63, wv = tid >> 6;

    f32x4 acc = (f32x4){0.f, 0.f, 0.f, 0.f};

    for (int it = 0; it < 16; ++it) {
        int tt = wv * 16 + it;                   // k>>5
        half8 a  = *(const half8*)(XF  + (size_t)((tt * 2 + bt) * 64 + lane) * 8);
        half8 bv = *(const half8*)(whF + (size_t)((tt * 16 + nb) * 64 + lane) * 8);
        acc = __builtin_amdgcn_mfma_f32_16x16x32_f16(a, bv, acc, 0, 0, 0);
    }

    for (int r = 0; r < 4; ++r)
        red[wv][lane][r] = acc[r];
    __syncthreads();

    if (tid < 256) {
        int lane2 = tid & 63, r = tid >> 6;
        float s = 0.f;
        for (int w = 0; w < 8; ++w) s += red[w][lane2][r];
        int batch = bt * 16 + ((lane2 >> 4) << 2) + r;
        int f = nb * 16 + (lane2 & 15);
        out[batch * 256 + f] = s + fc_b[f];
    }
}

// ---------------------------------------------------------------------------
extern "C" void kernel_launch(void* const* d_in, const int* in_sizes, int n_in,
                              void* d_out, int out_size, void* d_ws, size_t ws_size,
                              hipStream_t stream) {
    const float* x    = (const float*)d_in[0];
    const float* fc_w = (const float*)d_in[1];
    const float* fc_b = (const float*)d_in[2];
    float* out = (float*)d_out;

    char* ws = (char*)d_ws;
    _Float16* PF  = (_Float16*)(ws);                 // 4194304 B
    _Float16* XF  = (_Float16*)(ws + 4194304);       //  262144 B
    _Float16* whF = (_Float16*)(ws + 4456448);       // 2097152 B -> ~6.3 MiB

    k1<<<dim3(33, 32), 256, 0, stream>>>(x, fc_w, PF, whF);
    k2<<<dim3(4, 32),  256, 0, stream>>>(PF, XF);
    k3<<<32, 512, 0, stream>>>(XF, whF, fc_b, out);
}